// Round 6
// baseline (1067.203 us; speedup 1.0000x reference)
//
#include <hip/hip_runtime.h>

constexpr int B_ = 64, N_ = 32, I_ = 1152, D_ = 16, K_ = 8;
constexpr int SVD = B_ * N_ * D_;   // 32768

// Block: 256 thr = 4 waves; block covers (ic chunk of ICLEN i's) x (bg: 16 batches).
// Wave w: 4 batches; lane -> (n = l&31, d-half = l>>5). Softmax in-wave (shfl).
// W slice (16KB) single-buffered in LDS w/ XOR swizzle; x chunk staged once.
// MODE 0: c = 1/32 (folded into reduce scale). MODE 1: c = softmax_n(uh . veff).
template <int MODE, int NIC>
__global__ __launch_bounds__(256, 3) void route5(
    const float* __restrict__ W, const float* __restrict__ x,
    const float* __restrict__ veff, float* __restrict__ partial)
{
    constexpr int ICLEN = I_ / NIC;
    __shared__ __align__(16) float wlds[4096];               // 16KB W slice
    __shared__ __align__(16) float xlds[16 * ICLEN * K_];    // x chunk

    int bid = blockIdx.x;
    int ic, bg;
    if constexpr ((NIC & 7) == 0) {
        constexpr int icpx = NIC / 8;          // ic's per XCD (L2 locality)
        int x8 = bid & 7, r = bid >> 3;
        ic = x8 * icpx + (r % icpx);
        bg = r / icpx;
    } else { ic = bid >> 2; bg = bid & 3; }

    const int tid = threadIdx.x;
    const int w = tid >> 6, l = tid & 63;
    const int n = l & 31, dh = l >> 5, d0 = dh * 8;
    const int bBlk = bg * 16;          // block's batch base
    const int bB = bBlk + w * 4;       // this wave's batch base
    const int i0 = ic * ICLEN;

    // ---- stage x[bBlk..+16][i0..+ICLEN][0..8] into LDS (coalesced float4) ----
    // BUGFIX (round 3-5 fail): source batch base must be bBlk (block base),
    // NOT bB (wave base) — b already enumerates the block's 16 batches.
    constexpr int NF4 = 16 * ICLEN * 2;
    for (int s = tid; s < NF4; s += 256) {
        int b = s / (ICLEN * 2), f = s % (ICLEN * 2);
        float4 v = *(const float4*)(x + ((size_t)(bBlk + b) * I_ + i0) * K_ + f * 4);
        *(float4*)&xlds[b * (ICLEN * 8) + f * 4] = v;
    }

    // veff fragment in f32 (precision-critical: feeds the chaotic logit loop)
    float ve[4][8];
    if constexpr (MODE == 1) {
#pragma unroll
        for (int bb = 0; bb < 4; ++bb) {
            const float* vp = veff + ((bB + bb) * N_ + n) * D_ + d0;
            float4 a = *(const float4*)vp, b = *(const float4*)(vp + 4);
            ve[bb][0] = a.x;  ve[bb][1] = a.y;  ve[bb][2] = a.z;  ve[bb][3] = a.w;
            ve[bb][4] = b.x;  ve[bb][5] = b.y;  ve[bb][6] = b.z;  ve[bb][7] = b.w;
        }
    }

    // W staging: thread stages row nsl (=n), f4 pieces p0+8r, XOR-swizzled
    const int nsl = tid >> 3, p0 = tid & 7;
    const float* wrow = W + (size_t)nsl * (I_ * D_ * K_) + (size_t)i0 * 128;
    const int lsw = nsl & 7;

    float sacc[4][8];
#pragma unroll
    for (int bb = 0; bb < 4; ++bb)
#pragma unroll
        for (int j = 0; j < 8; ++j) sacc[bb][j] = 0.f;

    float4 st[4];
#pragma unroll
    for (int r = 0; r < 4; ++r) st[r] = *(const float4*)(wrow + (p0 + 8 * r) * 4);

#pragma unroll
    for (int t = 0; t < ICLEN; ++t) {
        __syncthreads();              // prev slice fully read; x-stage visible (t=0)
#pragma unroll
        for (int r = 0; r < 4; ++r)
            *(float4*)&wlds[(nsl * 32 + ((p0 + 8 * r) ^ lsw)) * 4] = st[r];
        if (t + 1 < ICLEN) {
#pragma unroll
            for (int r = 0; r < 4; ++r)    // prefetch next slice during compute
                st[r] = *(const float4*)(wrow + (t + 1) * 128 + (p0 + 8 * r) * 4);
        }
        __syncthreads();              // stage visible

        float uh[4][8];
        if constexpr (MODE == 1) {
#pragma unroll
            for (int bb = 0; bb < 4; ++bb)
#pragma unroll
                for (int j = 0; j < 8; ++j) uh[bb][j] = 0.f;
        }

#pragma unroll
        for (int kh = 0; kh < 2; ++kh) {
            float xr[4][4];
#pragma unroll
            for (int bb = 0; bb < 4; ++bb) {
                float4 xv = *(const float4*)&xlds[(w * 4 + bb) * (ICLEN * 8) + t * 8 + kh * 4];
                xr[bb][0] = xv.x; xr[bb][1] = xv.y; xr[bb][2] = xv.z; xr[bb][3] = xv.w;
            }
#pragma unroll
            for (int j = 0; j < 8; ++j) {
                int m = (((d0 + j) * 2 + kh) ^ (n & 7));
                float4 wv = *(const float4*)&wlds[(n * 32 + m) * 4];
#pragma unroll
                for (int bb = 0; bb < 4; ++bb) {
                    float acc = wv.x * xr[bb][0] + wv.y * xr[bb][1] +
                                wv.z * xr[bb][2] + wv.w * xr[bb][3];
                    if constexpr (MODE == 0) sacc[bb][j] += acc;
                    else                     uh[bb][j] += acc;
                }
            }
        }

        if constexpr (MODE == 1) {
#pragma unroll
            for (int bb = 0; bb < 4; ++bb) {
                float blp = 0.f;
#pragma unroll
                for (int j = 0; j < 8; ++j) blp += uh[bb][j] * ve[bb][j];
                blp += __shfl_xor(blp, 32);        // full-D dot
                float mx = blp;
#pragma unroll
                for (int s2 = 16; s2 >= 1; s2 >>= 1) mx = fmaxf(mx, __shfl_xor(mx, s2));
                float e = __expf(blp - mx), sm = e;
#pragma unroll
                for (int s2 = 16; s2 >= 1; s2 >>= 1) sm += __shfl_xor(sm, s2);
                float c = e / sm;
#pragma unroll
                for (int j = 0; j < 8; ++j) sacc[bb][j] = fmaf(c, uh[bb][j], sacc[bb][j]);
            }
        }
    }

    // flush partial (f32, 2x float4 per lane per bb), fully coalesced
#pragma unroll
    for (int bb = 0; bb < 4; ++bb) {
        float* pb = partial + ((size_t)ic * 4096 + (bB + bb) * 64 + n * 2 + dh) * 8;
        *(float4*)pb       = make_float4(sacc[bb][0], sacc[bb][1], sacc[bb][2], sacc[bb][3]);
        *(float4*)(pb + 4) = make_float4(sacc[bb][4], sacc[bb][5], sacc[bb][6], sacc[bb][7]);
    }
}

// Reduce NIC f32 partials + squash, fused output stage.
// 256 thr = 32 output-octets x 8 ic-parts; shfl_xor tree combines parts.
// RM 0: vout=squash  1: vout=vprev+squash  2: out=sigmoid(squash*dw+db)
template <int RM, int NIC>
__global__ __launch_bounds__(256) void reduce5(
    const float* __restrict__ partial, float scale,
    const float* __restrict__ vprev, float* __restrict__ vout,
    const float* __restrict__ dw, const float* __restrict__ db,
    float* __restrict__ out)
{
    int t = threadIdx.x;
    int oct = blockIdx.x * 32 + (t >> 3);
    int p = t & 7;
    int q0 = (p * NIC) >> 3, q1 = ((p + 1) * NIC) >> 3;
    float acc[8] = {0, 0, 0, 0, 0, 0, 0, 0};
    const float* base = partial + (size_t)oct * 8;
    for (int q = q0; q < q1; ++q) {
        float4 a = *(const float4*)(base + (size_t)q * 32768);
        float4 b = *(const float4*)(base + (size_t)q * 32768 + 4);
        acc[0] += a.x; acc[1] += a.y; acc[2] += a.z; acc[3] += a.w;
        acc[4] += b.x; acc[5] += b.y; acc[6] += b.z; acc[7] += b.w;
    }
#pragma unroll
    for (int s2 = 1; s2 <= 4; s2 <<= 1)
#pragma unroll
        for (int j = 0; j < 8; ++j) acc[j] += __shfl_xor(acc[j], s2);

    if (p == 0) {
        float vv[8];
#pragma unroll
        for (int j = 0; j < 8; ++j) {
            float ss = acc[j] * scale;
            float sq = ss * ss;
            float sc = sq / (1.f + sq) / sqrtf(sq + 1e-7f);
            vv[j] = sc * ss;
        }
        int ob = oct * 8;
        if constexpr (RM == 0) {
            *(float4*)&vout[ob]     = make_float4(vv[0], vv[1], vv[2], vv[3]);
            *(float4*)&vout[ob + 4] = make_float4(vv[4], vv[5], vv[6], vv[7]);
        } else if constexpr (RM == 1) {
            float4 a = *(const float4*)&vprev[ob], b = *(const float4*)&vprev[ob + 4];
            *(float4*)&vout[ob]     = make_float4(a.x + vv[0], a.y + vv[1], a.z + vv[2], a.w + vv[3]);
            *(float4*)&vout[ob + 4] = make_float4(b.x + vv[4], b.y + vv[5], b.z + vv[6], b.w + vv[7]);
        } else {
            float dwv = dw[0], dbv = db[0];
#pragma unroll
            for (int j = 0; j < 8; ++j)
                out[ob + j] = 1.f / (1.f + __expf(-(vv[j] * dwv + dbv)));
        }
    }
}

template <int NIC>
static void run_pipeline(const float* W, const float* x, const float* dw,
                         const float* db, float* out, void* d_ws, hipStream_t stream)
{
    float* partial = (float*)d_ws;
    float* vA = partial + (size_t)NIC * 32768;
    float* vB = vA + SVD;
    dim3 rblk(256), rgrid(NIC * 4), dgrid(SVD / 8 / 32);

    route5<0, NIC><<<rgrid, rblk, 0, stream>>>(W, x, nullptr, partial);
    reduce5<0, NIC><<<dgrid, rblk, 0, stream>>>(partial, 1.f / 32.f, nullptr, vA, nullptr, nullptr, nullptr);
    route5<1, NIC><<<rgrid, rblk, 0, stream>>>(W, x, vA, partial);
    reduce5<1, NIC><<<dgrid, rblk, 0, stream>>>(partial, 1.f, vA, vB, nullptr, nullptr, nullptr);
    route5<1, NIC><<<rgrid, rblk, 0, stream>>>(W, x, vB, partial);
    reduce5<2, NIC><<<dgrid, rblk, 0, stream>>>(partial, 1.f, nullptr, nullptr, dw, db, out);
}

extern "C" void kernel_launch(void* const* d_in, const int* in_sizes, int n_in,
                              void* d_out, int out_size, void* d_ws, size_t ws_size,
                              hipStream_t stream)
{
    const float* x  = (const float*)d_in[0];
    const float* W  = (const float*)d_in[1];
    const float* dw = (const float*)d_in[2];
    const float* db = (const float*)d_in[3];
    float* out = (float*)d_out;

    // f32 partials: NIC=192 needs 192*128KB = 24.6MB (+256KB v).
    const size_t needMain = (size_t)192 * 32768 * 4 + 2ull * SVD * 4;
    if (ws_size >= needMain)
        run_pipeline<192>(W, x, dw, db, out, d_ws, stream);   // grid 768 = 3 blk/CU
    else
        run_pipeline<36>(W, x, dw, db, out, d_ws, stream);    // ~4.7MB fallback
}

// Round 8
// 159.640 us; speedup vs baseline: 6.6851x; 6.6851x over previous
//
#include <hip/hip_runtime.h>

constexpr int B_ = 64, N_ = 32, I_ = 1152, D_ = 16, K_ = 8;
constexpr int SVD = B_ * N_ * D_;   // 32768

// Block: 256 thr = 4 waves; block = (ic chunk of ICLEN i's) x (bg: 16 batches).
// Wave w: batches bB..bB+3; lane -> (n = l&31, d-half = l>>5). Softmax in-wave (shfl).
// W slice (16KB/i) double-buffered in LDS with ROTATION swizzle:
//   row n granule g (16B) stored at slot ((g + n) & 31) -> 0 extra bank conflicts.
// Softmax KEEPS max-subtraction: iter-2 logits are N(0, sigma~20) (veff=v0+v1,
// v elements saturate near +-1 and correlate with uh) -> exp(raw) overflows f32
// for ~1e1 of the 2.4M logits (round-7 NaN). Shift by max is mandatory.
// MODE 0: c = 1/32 (folded into reduce scale). MODE 1: c = softmax_n(uh . veff).
template <int MODE, int NIC>
__global__ __launch_bounds__(256, 2) void route7(
    const float* __restrict__ W, const float* __restrict__ x,
    const float* __restrict__ veff, float* __restrict__ partial)
{
    constexpr int ICLEN = I_ / NIC;
    __shared__ __align__(16) float wlds[2][4096];   // 2 x 16KB

    int bid = blockIdx.x;
    int ic, bg;
    if constexpr ((NIC & 7) == 0) {
        constexpr int icpx = NIC / 8;          // ic's per XCD (W slice stays L2-local)
        int x8 = bid & 7, r = bid >> 3;
        ic = x8 * icpx + (r % icpx);
        bg = r / icpx;
    } else { ic = bid >> 2; bg = bid & 3; }

    const int tid = threadIdx.x;
    const int w = tid >> 6, l = tid & 63;
    const int n = l & 31, dh = l >> 5, d0 = dh * 8;
    const int bB = bg * 16 + w * 4;
    const int i0 = ic * ICLEN;

    // veff fragment (f32, registers)
    float ve[4][8];
    if constexpr (MODE == 1) {
#pragma unroll
        for (int bb = 0; bb < 4; ++bb) {
            const float* vp = veff + ((bB + bb) * N_ + n) * D_ + d0;
            float4 a = *(const float4*)vp, b = *(const float4*)(vp + 4);
            ve[bb][0] = a.x;  ve[bb][1] = a.y;  ve[bb][2] = a.z;  ve[bb][3] = a.w;
            ve[bb][4] = b.x;  ve[bb][5] = b.y;  ve[bb][6] = b.z;  ve[bb][7] = b.w;
        }
    }

    // W staging: thread stages row nsl, granules p0+8r (16B), rotation-swizzled
    const int nsl = tid >> 3, p0 = tid & 7;
    const float* wrow = W + (size_t)nsl * (I_ * D_ * K_) + (size_t)i0 * 128;

    float sacc[4][8];
#pragma unroll
    for (int bb = 0; bb < 4; ++bb)
#pragma unroll
        for (int j = 0; j < 8; ++j) sacc[bb][j] = 0.f;

    float4 st[4];
    auto stage_load = [&](int t) {
#pragma unroll
        for (int r = 0; r < 4; ++r)
            st[r] = *(const float4*)(wrow + (size_t)t * 128 + (p0 + 8 * r) * 4);
    };
    auto stage_write = [&](int buf) {
#pragma unroll
        for (int r = 0; r < 4; ++r) {
            int g = p0 + 8 * r;
            *(float4*)&wlds[buf][nsl * 128 + ((g + nsl) & 31) * 4] = st[r];
        }
    };

    stage_load(0);
    stage_write(0);

    for (int t = 0; t < ICLEN; ++t) {
        __syncthreads();                               // buf(t&1) staged & prev reads done
        if (t + 1 < ICLEN) stage_load(t + 1);          // VMEM overlaps compute
        const int buf = t & 1;
        const int i = i0 + t;

        // x[b, i, :] — wave-uniform broadcast loads (2.3MB total, L2-hot)
        float xr[4][8];
#pragma unroll
        for (int bb = 0; bb < 4; ++bb) {
            const float* xp = x + ((size_t)(bB + bb) * I_ + i) * K_;
            float4 a = *(const float4*)xp, c4 = *(const float4*)(xp + 4);
            xr[bb][0] = a.x;  xr[bb][1] = a.y;  xr[bb][2] = a.z;  xr[bb][3] = a.w;
            xr[bb][4] = c4.x; xr[bb][5] = c4.y; xr[bb][6] = c4.z; xr[bb][7] = c4.w;
        }

        float uh[4][8];
#pragma unroll
        for (int j = 0; j < 8; ++j) {
            int g0 = (d0 + j) * 2;                     // two 16B granules of row n
            float4 wa = *(const float4*)&wlds[buf][n * 128 + (((g0)     + n) & 31) * 4];
            float4 wb = *(const float4*)&wlds[buf][n * 128 + (((g0 + 1) + n) & 31) * 4];
#pragma unroll
            for (int bb = 0; bb < 4; ++bb) {
                float acc = wa.x * xr[bb][0] + wa.y * xr[bb][1] +
                            wa.z * xr[bb][2] + wa.w * xr[bb][3] +
                            wb.x * xr[bb][4] + wb.y * xr[bb][5] +
                            wb.z * xr[bb][6] + wb.w * xr[bb][7];
                if constexpr (MODE == 0) sacc[bb][j] += acc;
                else                     uh[bb][j] = acc;
            }
        }

        if constexpr (MODE == 1) {
#pragma unroll
            for (int bb = 0; bb < 4; ++bb) {
                float blp = 0.f;
#pragma unroll
                for (int j = 0; j < 8; ++j) blp += uh[bb][j] * ve[bb][j];
                blp += __shfl_xor(blp, 32);            // full-D dot
                float mx = blp;                        // max over n (overflow guard)
#pragma unroll
                for (int s2 = 16; s2 >= 1; s2 >>= 1) mx = fmaxf(mx, __shfl_xor(mx, s2));
                float e = __expf(blp - mx), sm = e;
#pragma unroll
                for (int s2 = 16; s2 >= 1; s2 >>= 1) sm += __shfl_xor(sm, s2);
                float c = e / sm;
#pragma unroll
                for (int j = 0; j < 8; ++j) sacc[bb][j] = fmaf(c, uh[bb][j], sacc[bb][j]);
            }
        }

        if (t + 1 < ICLEN) stage_write((t + 1) & 1);
    }

    // flush partial: partial[ic][b][n][d], dense float4x2 per lane per bb
#pragma unroll
    for (int bb = 0; bb < 4; ++bb) {
        float* pb = partial + (size_t)ic * 32768 + (bB + bb) * 512 + n * 16 + d0;
        *(float4*)pb       = make_float4(sacc[bb][0], sacc[bb][1], sacc[bb][2], sacc[bb][3]);
        *(float4*)(pb + 4) = make_float4(sacc[bb][4], sacc[bb][5], sacc[bb][6], sacc[bb][7]);
    }
}

// Reduce NIC partials + squash, one thread per output element (coalesced 1KB/wave/step).
// RM 0: vout=squash  1: vout=vprev+squash  2: out=sigmoid(squash*dw+db)
template <int RM, int NIC>
__global__ __launch_bounds__(256) void reduce7(
    const float* __restrict__ partial, float scale,
    const float* __restrict__ vprev, float* __restrict__ vout,
    const float* __restrict__ dw, const float* __restrict__ db,
    float* __restrict__ out)
{
    int e = blockIdx.x * 256 + threadIdx.x;           // grid 128 -> 32768 elems
    float a0 = 0.f, a1 = 0.f, a2 = 0.f, a3 = 0.f;
    const float* p = partial + e;
#pragma unroll 2
    for (int q = 0; q + 4 <= NIC; q += 4) {
        a0 += p[(size_t)(q + 0) * 32768];
        a1 += p[(size_t)(q + 1) * 32768];
        a2 += p[(size_t)(q + 2) * 32768];
        a3 += p[(size_t)(q + 3) * 32768];
    }
    if constexpr (NIC & 3) {
        for (int q = NIC & ~3; q < NIC; ++q) a0 += p[(size_t)q * 32768];
    }
    float ss = ((a0 + a1) + (a2 + a3)) * scale;

    float sq = ss * ss;
    float sc = sq / (1.f + sq) / sqrtf(sq + 1e-7f);
    float v = sc * ss;
    if constexpr (RM == 0) {
        vout[e] = v;
    } else if constexpr (RM == 1) {
        vout[e] = vprev[e] + v;
    } else {
        float z = v * dw[0] + db[0];
        out[e] = 1.f / (1.f + __expf(-z));
    }
}

template <int NIC>
static void run_pipeline(const float* W, const float* x, const float* dw,
                         const float* db, float* out, void* d_ws, hipStream_t stream)
{
    float* partial = (float*)d_ws;
    float* vA = partial + (size_t)NIC * 32768;
    float* vB = vA + SVD;
    dim3 rblk(256), rgrid(NIC * 4), dgrid(SVD / 256);

    route7<0, NIC><<<rgrid, rblk, 0, stream>>>(W, x, nullptr, partial);
    reduce7<0, NIC><<<dgrid, rblk, 0, stream>>>(partial, 1.f / 32.f, nullptr, vA, nullptr, nullptr, nullptr);
    route7<1, NIC><<<rgrid, rblk, 0, stream>>>(W, x, vA, partial);
    reduce7<1, NIC><<<dgrid, rblk, 0, stream>>>(partial, 1.f, vA, vB, nullptr, nullptr, nullptr);
    route7<1, NIC><<<rgrid, rblk, 0, stream>>>(W, x, vB, partial);
    reduce7<2, NIC><<<dgrid, rblk, 0, stream>>>(partial, 1.f, nullptr, nullptr, dw, db, out);
}

extern "C" void kernel_launch(void* const* d_in, const int* in_sizes, int n_in,
                              void* d_out, int out_size, void* d_ws, size_t ws_size,
                              hipStream_t stream)
{
    const float* x  = (const float*)d_in[0];
    const float* W  = (const float*)d_in[1];
    const float* dw = (const float*)d_in[2];
    const float* db = (const float*)d_in[3];
    float* out = (float*)d_out;

    const size_t needMain = (size_t)192 * 32768 * 4 + 2ull * SVD * 4;   // ~25MB
    if (ws_size >= needMain)
        run_pipeline<192>(W, x, dw, db, out, d_ws, stream);   // grid 768 = 3 blk/CU
    else
        run_pipeline<36>(W, x, dw, db, out, d_ws, stream);    // ~4.9MB fallback
}